// Round 8
// baseline (571.722 us; speedup 1.0000x reference)
//
#include <hip/hip_runtime.h>
#include <math.h>

// Problem constants
#define NB 16      // batch
#define NE 128     // experts / channels
#define NK 8
#define HW 16384   // 128*128
#define NPIX (NB * HW)

// f32 transposed gate weights: gwT[e][f] = gate_w[f][e]
__device__ __align__(16) float g_gwT[NE * NE];

__global__ __launch_bounds__(256) void cvt_gw_kernel(const float* __restrict__ gate_w) {
    int i = blockIdx.x * 256 + threadIdx.x;   // i = e*128 + f
    if (i < NE * NE) {
        int e = i >> 7;
        int f = i & 127;
        g_gwT[i] = gate_w[f * NE + e];
    }
}

// Broadcast-compute one row PAIR (rows 2p, 2p+1) held in GBUF:
// lane l<32 holds row 2p floats [4l..4l+3]; lane 32+l holds row 2p+1 same.
// readlane -> SGPR feeds v_fma as its single scalar operand. gw bits and the
// per-f ascending-e chain are identical to the passing round-2 kernel.
#define PAIR_COMPUTE(GBUF, XE0, XE1)                                                     \
    {                                                                                    \
        _Pragma("unroll")                                                                \
        for (int j = 0; j < 32; ++j) {                                                   \
            float w0 = __int_as_float(__builtin_amdgcn_readlane(__float_as_int(GBUF.x), j)); \
            float w1 = __int_as_float(__builtin_amdgcn_readlane(__float_as_int(GBUF.y), j)); \
            float w2 = __int_as_float(__builtin_amdgcn_readlane(__float_as_int(GBUF.z), j)); \
            float w3 = __int_as_float(__builtin_amdgcn_readlane(__float_as_int(GBUF.w), j)); \
            acc[4 * j + 0] = fmaf(w0, XE0, acc[4 * j + 0]);                              \
            acc[4 * j + 1] = fmaf(w1, XE0, acc[4 * j + 1]);                              \
            acc[4 * j + 2] = fmaf(w2, XE0, acc[4 * j + 2]);                              \
            acc[4 * j + 3] = fmaf(w3, XE0, acc[4 * j + 3]);                              \
        }                                                                                \
        _Pragma("unroll")                                                                \
        for (int j = 0; j < 32; ++j) {                                                   \
            float w0 = __int_as_float(__builtin_amdgcn_readlane(__float_as_int(GBUF.x), 32 + j)); \
            float w1 = __int_as_float(__builtin_amdgcn_readlane(__float_as_int(GBUF.y), 32 + j)); \
            float w2 = __int_as_float(__builtin_amdgcn_readlane(__float_as_int(GBUF.z), 32 + j)); \
            float w3 = __int_as_float(__builtin_amdgcn_readlane(__float_as_int(GBUF.w), 32 + j)); \
            acc[4 * j + 0] = fmaf(w0, XE1, acc[4 * j + 0]);                              \
            acc[4 * j + 1] = fmaf(w1, XE1, acc[4 * j + 1]);                              \
            acc[4 * j + 2] = fmaf(w2, XE1, acc[4 * j + 2]);                              \
            acc[4 * j + 3] = fmaf(w3, XE1, acc[4 * j + 3]);                              \
        }                                                                                \
    }

__global__ __launch_bounds__(256) void moe_kernel(const float* __restrict__ experts,
                                                  const float* __restrict__ gate_b,
                                                  float* __restrict__ out) {
    const int tid  = threadIdx.x;
    const int lane = tid & 63;
    const int p    = blockIdx.x * 256 + tid;         // pixel id
    const int n    = p >> 14;                        // /16384
    const int hw   = p & (HW - 1);

    const float* xp = experts + ((size_t)n * NE * HW + hw);   // channel stride HW

    // per-lane gw pair pointer: pair p covers float4 indices [p*64, p*64+64)
    const float4* gwq = ((const float4*)g_gwT) + lane;

    float acc[NE];
#pragma unroll
    for (int f = 0; f < NE; ++f) acc[f] = 0.0f;

    // xe via 8-deep register rotation of coalesced global loads (proven no-spill)
    float xr[8], xn[8];
#pragma unroll
    for (int i = 0; i < 8; ++i) xr[i] = xp[(size_t)i * HW];

    // gw row-pair double buffer (ping-pong named float4s)
    float4 ga = gwq[0];   // pair 0 = rows 0,1
    float4 gb;

    for (int g = 0; g < 16; ++g) {        // 16 groups of 8 channels (4 pairs each)
        if (g < 15) {                     // prefetch next x chunk
            const float* xq = xp + (size_t)(g + 1) * 8 * HW;
#pragma unroll
            for (int i = 0; i < 8; ++i) xn[i] = xq[(size_t)i * HW];
        }
        // pair 4g+0 from ga, prefetch 4g+1 -> gb
        gb = gwq[(size_t)(4 * g + 1) * 64];
        PAIR_COMPUTE(ga, xr[0], xr[1]);
        // pair 4g+1 from gb, prefetch 4g+2 -> ga
        ga = gwq[(size_t)(4 * g + 2) * 64];
        PAIR_COMPUTE(gb, xr[2], xr[3]);
        // pair 4g+2 from ga, prefetch 4g+3 -> gb
        gb = gwq[(size_t)(4 * g + 3) * 64];
        PAIR_COMPUTE(ga, xr[4], xr[5]);
        // pair 4g+3 from gb, prefetch 4g+4 -> ga (guard the very last)
        if (4 * g + 4 < 64) ga = gwq[(size_t)(4 * g + 4) * 64];
        PAIR_COMPUTE(gb, xr[6], xr[7]);

        if (g < 15) {
#pragma unroll
            for (int i = 0; i < 8; ++i) xr[i] = xn[i];
        }
    }

    // ---- + bias (zeros here; mirrored for fidelity) ----
#pragma unroll
    for (int f = 0; f < NE; ++f) acc[f] = acc[f] + gate_b[f];

    // ---- softmax, f32 numpy semantics (bit-frozen) ----
    float m = acc[0];
#pragma unroll
    for (int f = 1; f < NE; ++f) m = fmaxf(m, acc[f]);

    // correctly-rounded f32 exp of (l - m)
#pragma unroll
    for (int f = 0; f < NE; ++f) {
        acc[f] = (float)exp((double)(acc[f] - m));
    }

    // denominator: sequential ascending f32 sum (np strided-axis reduce order)
    float s = acc[0];
#pragma unroll
    for (int f = 1; f < NE; ++f) s = s + acc[f];

    // routing weights: IEEE f32 divide (ranking happens in w space -> mirror it)
#pragma unroll
    for (int f = 0; f < NE; ++f) acc[f] = acc[f] / s;

    // ---- top-8 on (w desc, idx asc): ascending-f insertion, strict '>' ----
    float t_v[NK];
    int   t_i[NK];
#pragma unroll
    for (int i = 0; i < NK; ++i) { t_v[i] = -1.0f; t_i[i] = 0; }

#pragma unroll
    for (int f = 0; f < NE; ++f) {
        float v  = acc[f];
        int   ix = f;
#pragma unroll
        for (int i = 0; i < NK; ++i) {
            bool gt = v > t_v[i];
            float tv = t_v[i]; int ti = t_i[i];
            t_v[i] = gt ? v  : tv;
            t_i[i] = gt ? ix : ti;
            v      = gt ? tv : v;
            ix     = gt ? ti : ix;
        }
    }

    // ---- gather + scale + write ----
    float* op = out + ((size_t)n * NK * HW + hw);
#pragma unroll
    for (int k = 0; k < NK; ++k) {
        float xv = xp[(size_t)t_i[k] * HW];
        op[(size_t)k * HW] = t_v[k] * xv;
    }
}

extern "C" void kernel_launch(void* const* d_in, const int* in_sizes, int n_in,
                              void* d_out, int out_size, void* d_ws, size_t ws_size,
                              hipStream_t stream) {
    // inputs: 0=x (unused), 1=experts [N,E,H,W] f32, 2=gate_w [E,E] f32, 3=gate_b [E] f32
    const float* experts = (const float*)d_in[1];
    const float* gate_w  = (const float*)d_in[2];
    const float* gate_b  = (const float*)d_in[3];
    float* out = (float*)d_out;

    hipLaunchKernelGGL(cvt_gw_kernel, dim3((NE * NE + 255) / 256), dim3(256), 0, stream, gate_w);
    hipLaunchKernelGGL(moe_kernel, dim3(NPIX / 256), dim3(256), 0, stream, experts, gate_b, out);
}

// Round 9
// 383.414 us; speedup vs baseline: 1.4911x; 1.4911x over previous
//
#include <hip/hip_runtime.h>
#include <math.h>

// Problem constants
#define NB 16      // batch
#define NE 128     // experts / channels
#define NK 8
#define HW 16384   // 128*128
#define NPIX (NB * HW)

// f32 transposed gate weights: gwT[e][f] = gate_w[f][e]
__device__ float g_gwT[NE * NE];

__global__ __launch_bounds__(256) void cvt_gw_kernel(const float* __restrict__ gate_w) {
    int i = blockIdx.x * 256 + threadIdx.x;   // i = e*128 + f
    if (i < NE * NE) {
        int e = i >> 7;
        int f = i & 127;
        g_gwT[i] = gate_w[f * NE + e];
    }
}

__global__ __launch_bounds__(256, 2) void moe_kernel(const float* __restrict__ experts,
                                                     const float* __restrict__ gate_b,
                                                     float* __restrict__ out) {
    const int tid = threadIdx.x;
    const int p   = blockIdx.x * 256 + tid;          // pixel id
    const int n   = p >> 14;                         // /16384
    const int hw  = p & (HW - 1);

    const float* xp = experts + ((size_t)n * NE * HW + hw);   // channel stride HW

    // ---- one-time stage: gwT (64 KB) into LDS, bit-preserving ----
    __shared__ __align__(16) float gws[NE * NE];
    {
        const float4* src = (const float4*)g_gwT;
        float4* dst = (float4*)gws;
#pragma unroll
        for (int i = 0; i < 16; ++i) {           // 4096 float4 total, 16 per thread
            dst[tid + 256 * i] = src[tid + 256 * i];
        }
    }
    __syncthreads();   // only barrier in the kernel

    float acc[NE];
#pragma unroll
    for (int f = 0; f < NE; ++f) acc[f] = 0.0f;

    // ---- logits: ascending-e fmaf chain (bit-identical to round 2) ----
    // gw rows from LDS (uniform-address broadcast ds_read_b128),
    // xe via 8-deep register rotation of coalesced global loads.
    float xr[8];
#pragma unroll
    for (int i = 0; i < 8; ++i) xr[i] = xp[(size_t)i * HW];

    for (int eg = 0; eg < 16; ++eg) {            // 16 groups of 8 channels
        float xn[8];
        if (eg < 15) {
            const float* xq = xp + (size_t)(eg + 1) * 8 * HW;
#pragma unroll
            for (int i = 0; i < 8; ++i) xn[i] = xq[(size_t)i * HW];
        }
#pragma unroll
        for (int i = 0; i < 8; ++i) {
            const float xe = xr[i];
            const float4* grow = (const float4*)&gws[(eg * 8 + i) * NE];
#pragma unroll
            for (int j = 0; j < NE / 4; ++j) {
                float4 g = grow[j];
                acc[4 * j + 0] = fmaf(g.x, xe, acc[4 * j + 0]);
                acc[4 * j + 1] = fmaf(g.y, xe, acc[4 * j + 1]);
                acc[4 * j + 2] = fmaf(g.z, xe, acc[4 * j + 2]);
                acc[4 * j + 3] = fmaf(g.w, xe, acc[4 * j + 3]);
            }
        }
        if (eg < 15) {
#pragma unroll
            for (int i = 0; i < 8; ++i) xr[i] = xn[i];
        }
    }

    // ---- + bias (zeros here; mirrored for fidelity) ----
#pragma unroll
    for (int f = 0; f < NE; ++f) acc[f] = acc[f] + gate_b[f];

    // ---- softmax, f32 numpy semantics (bit-frozen) ----
    float m = acc[0];
#pragma unroll
    for (int f = 1; f < NE; ++f) m = fmaxf(m, acc[f]);

    // correctly-rounded f32 exp of (l - m)
#pragma unroll
    for (int f = 0; f < NE; ++f) {
        acc[f] = (float)exp((double)(acc[f] - m));
    }

    // denominator: sequential ascending f32 sum (np strided-axis reduce order)
    float s = acc[0];
#pragma unroll
    for (int f = 1; f < NE; ++f) s = s + acc[f];

    // routing weights: IEEE f32 divide (ranking happens in w space -> mirror it)
#pragma unroll
    for (int f = 0; f < NE; ++f) acc[f] = acc[f] / s;

    // ---- top-8 on (w desc, idx asc): ascending-f insertion, strict '>' ----
    float t_v[NK];
    int   t_i[NK];
#pragma unroll
    for (int i = 0; i < NK; ++i) { t_v[i] = -1.0f; t_i[i] = 0; }

#pragma unroll
    for (int f = 0; f < NE; ++f) {
        float v  = acc[f];
        int   ix = f;
#pragma unroll
        for (int i = 0; i < NK; ++i) {
            bool gt = v > t_v[i];
            float tv = t_v[i]; int ti = t_i[i];
            t_v[i] = gt ? v  : tv;
            t_i[i] = gt ? ix : ti;
            v      = gt ? tv : v;
            ix     = gt ? ti : ix;
        }
    }

    // ---- gather + scale + write ----
    float* op = out + ((size_t)n * NK * HW + hw);
#pragma unroll
    for (int k = 0; k < NK; ++k) {
        float xv = xp[(size_t)t_i[k] * HW];
        op[(size_t)k * HW] = t_v[k] * xv;
    }
}

extern "C" void kernel_launch(void* const* d_in, const int* in_sizes, int n_in,
                              void* d_out, int out_size, void* d_ws, size_t ws_size,
                              hipStream_t stream) {
    // inputs: 0=x (unused), 1=experts [N,E,H,W] f32, 2=gate_w [E,E] f32, 3=gate_b [E] f32
    const float* experts = (const float*)d_in[1];
    const float* gate_w  = (const float*)d_in[2];
    const float* gate_b  = (const float*)d_in[3];
    float* out = (float*)d_out;

    hipLaunchKernelGGL(cvt_gw_kernel, dim3((NE * NE + 255) / 256), dim3(256), 0, stream, gate_w);
    hipLaunchKernelGGL(moe_kernel, dim3(NPIX / 256), dim3(256), 0, stream, experts, gate_b, out);
}